// Round 11
// baseline (253.375 us; speedup 1.0000x reference)
//
#include <hip/hip_runtime.h>
#include <hip/hip_bf16.h>

#define DEVI __device__ __forceinline__

typedef __bf16 bf16x8 __attribute__((ext_vector_type(8)));
typedef float f32x4 __attribute__((ext_vector_type(4)));
typedef unsigned short u16x4 __attribute__((ext_vector_type(4)));
typedef unsigned int u32x2 __attribute__((ext_vector_type(2)));
typedef unsigned long long ull;
typedef ull u64x2 __attribute__((ext_vector_type(2)));

constexpr int Nn = 2, Ss = 2048, Ee = 1024, Hh = 16;
constexpr int Ms = Nn * Ss;                       // 4096 rows
constexpr float SCALE = 0.022097086912079608f;    // 1/sqrt(2048) -- key-length scaling!
constexpr int NCH = 524288;                       // 1KB mask chunks (537MB / 1KB)

// workspace layout (bf16 elements)
constexpr size_t SZ_X   = (size_t)Ms * Ee;        // 4,194,304
constexpr size_t EEc    = (size_t)Ee * Ee;
constexpr size_t OFF_QB = 0;                      // Q projected [Ms][Ee]
constexpr size_t OFF_KB = SZ_X;                   // K projected [Ms][Ee]
constexpr size_t OFF_VB = 2 * SZ_X;               // V projected TRANSPOSED [Ee][Ms]
constexpr size_t OFF_XQ = 3 * SZ_X;               // bf16 inputs (3)
constexpr size_t OFF_W  = 6 * SZ_X;               // 4 weights, each Ee*Ee
constexpr size_t OFF_PACK = 6 * SZ_X + 4 * EEc;   // bitmask, 16.8 MB
constexpr size_t OFF_ATTN = OFF_XQ;               // attention out aliases XQ (dead by then)

DEVI unsigned short f2bf(float f) {               // RNE f32->bf16 (no NaN in this data)
  unsigned int u = __builtin_bit_cast(unsigned int, f);
  u += 0x7fffu + ((u >> 16) & 1u);
  return (unsigned short)(u >> 16);
}

DEVI void async16(const void* g, void* l) {
  __builtin_amdgcn_global_load_lds(
      (const __attribute__((address_space(1))) void*)g,
      (__attribute__((address_space(3))) void*)l, 16, 0, 0);
}

DEVI f32x4 mfma_bf16(bf16x8 a, bf16x8 b, f32x4 c) {
  return __builtin_amdgcn_mfma_f32_16x16x32_bf16(a, b, c, 0, 0, 0);
}

DEVI unsigned cvt_pk_bf16(float lo, float hi) {   // v_cvt_pk_bf16_f32: [hi|lo]
  unsigned r;
  asm("v_cvt_pk_bf16_f32 %0, %1, %2" : "=v"(r) : "v"(lo), "v"(hi));
  return r;
}

// ---------------- fp32 -> bf16 convert, z-batched over up to 4 sources -------------
__global__ __launch_bounds__(256) void cvt_batch(
    const float* __restrict__ s0, const float* __restrict__ s1,
    const float* __restrict__ s2, const float* __restrict__ s3,
    unsigned short* __restrict__ dbase, size_t dstride, int n4)
{
  const float* s = (blockIdx.z == 0) ? s0 : (blockIdx.z == 1) ? s1
                 : (blockIdx.z == 2) ? s2 : s3;
  unsigned short* d = dbase + (size_t)blockIdx.z * dstride;
  const int i = blockIdx.x * 256 + threadIdx.x;
  if (i >= n4) return;
  const float4 v = reinterpret_cast<const float4*>(s)[i];
  u16x4 o = { f2bf(v.x), f2bf(v.y), f2bf(v.z), f2bf(v.w) };
  reinterpret_cast<u16x4*>(d)[i] = o;
}

// ---------------- fused QKV projections + mask pack, 1-deep pipelined --------------
// 768 blocks (3/CU): 0..511 Q/K projections, 512..767 V^T projection. Every block
// also streams a contiguous 768KB mask slab (24KB per k-step, the 6.3 TB/s pattern).
// Pipeline: staging double-buffered 1 step ahead; mask registers loaded 1 step
// ahead; ONE raw s_barrier per step with vmcnt(0) at step top -- issue-to-wait
// distance is a full step (~7000 cyc) >> HBM latency, so the wait lands on
// already-arrived data (this is what R10's issue-and-drain-same-step lacked).
__global__ __launch_bounds__(256, 3) void qkv_pack(
    const unsigned short* __restrict__ Xq,     // bf16 inputs base (3x)
    const unsigned short* __restrict__ W,      // bf16 weights base (4x)
    unsigned short* __restrict__ QKout,        // Q,K out (2x SZ_X)
    unsigned short* __restrict__ Vtout,        // V^T out [Ee][Ms]
    const int* __restrict__ mask,
    ull* __restrict__ P64)
{
  constexpr int K = 1024;
  __shared__ unsigned short As0[128 * 32], As1[128 * 32];
  __shared__ unsigned short Bs0[128 * 32], Bs1[128 * 32];
  const int b = blockIdx.x;

  const unsigned short *A, *B;
  unsigned short* C;
  int ldC, m0, n0;
  if (b < 512) {
    const int z = b >> 8, by = (b >> 3) & 31, bx = b & 7;
    A = Xq + (size_t)z * SZ_X;  B = W + (size_t)z * EEc;
    C = QKout + (size_t)z * SZ_X;  ldC = Ee;  m0 = by * 128;  n0 = bx * 128;
  } else {
    const int v = b - 512, bx = v & 31, by = v >> 5;
    A = W + 2 * EEc;  B = Xq + 2 * SZ_X;
    C = Vtout;  ldC = Ms;  m0 = by * 128;  n0 = bx * 128;
  }

  const int tid = threadIdx.x;
  const int lane = tid & 63, w = tid >> 6;
  const int lr = lane & 15, lg = lane >> 4;
  const int wr = (w >> 1) * 64, wc = (w & 1) * 64;

  // staging source addressing (per-thread constants except k0)
  const int i0 = 2 * w, i1 = 2 * w + 1;
  const int boff0 = i0 * 1024 + lane * 16, boff1 = i1 * 1024 + lane * 16;
  const int srow0 = boff0 >> 6, scol0 = boff0 & 63;
  const int srow1 = boff1 >> 6, scol1 = boff1 & 63;

  const f32x4 zero = {0.f, 0.f, 0.f, 0.f};
  f32x4 acc[4][4];
  for (int a = 0; a < 4; ++a)
    for (int c = 0; c < 4; ++c) acc[a][c] = zero;

  const int cblock = b * 768;                  // block's contiguous 768KB mask slab
  int pm[6][4];                                // mask regs for step s (1 set)

  auto stage = [&](int s, unsigned short* An, unsigned short* Bn) {
    const int k0 = s * 32;
    async16((const char*)A + ((size_t)(m0 + srow0) * K + k0) * 2 + scol0,
            (char*)An + i0 * 1024);
    async16((const char*)B + ((size_t)(n0 + srow0) * K + k0) * 2 + scol0,
            (char*)Bn + i0 * 1024);
    async16((const char*)A + ((size_t)(m0 + srow1) * K + k0) * 2 + scol1,
            (char*)An + i1 * 1024);
    async16((const char*)B + ((size_t)(n0 + srow1) * K + k0) * 2 + scol1,
            (char*)Bn + i1 * 1024);
  };
  auto mload = [&](int s) {
    const int cbase = cblock + s * 24 + w * 6;
#pragma unroll
    for (int i = 0; i < 6; ++i) {
      const int ch = cbase + i;
      if (ch < NCH) {
        const int* mp = mask + (size_t)ch * 256 + lane;
        pm[i][0] = __builtin_nontemporal_load(mp);
        pm[i][1] = __builtin_nontemporal_load(mp + 64);
        pm[i][2] = __builtin_nontemporal_load(mp + 128);
        pm[i][3] = __builtin_nontemporal_load(mp + 192);
      }
    }
  };

  // prologue: stage(0) -> buf0, mask(0) -> pm
  stage(0, As0, Bs0);
  mload(0);

  auto step = [&](int s, unsigned short* Ac, unsigned short* Bc,
                  unsigned short* An, unsigned short* Bn) {
    // stage(s) + mask(s) issued a full step ago -> already landed
    asm volatile("s_waitcnt vmcnt(0)" ::: "memory");
    __builtin_amdgcn_s_barrier();

    if (s + 1 < 32) stage(s + 1, An, Bn);

    // consume pack(s): ballots + 16B stores (mix with MFMAs below)
    {
      const int cbase = cblock + s * 24 + w * 6;
#pragma unroll
      for (int i = 0; i < 6; ++i) {
        const int ch = cbase + i;
        if (ch < NCH) {
          const ull b0 = __ballot(pm[i][0] != 0);
          const ull b1 = __ballot(pm[i][1] != 0);
          const ull b2 = __ballot(pm[i][2] != 0);
          const ull b3 = __ballot(pm[i][3] != 0);
          if (lane < 2) {
            u64x2 v;
            v[0] = lane == 0 ? b0 : b2;
            v[1] = lane == 0 ? b1 : b3;
            *(u64x2*)(P64 + (size_t)ch * 4 + lane * 2) = v;
          }
        }
      }
    }
    if (s + 1 < 32) mload(s + 1);        // refill pm (consumed above)

    // compute step s from Ac/Bc
    bf16x8 aF[4], bF[4];
#pragma unroll
    for (int rb = 0; rb < 4; ++rb)
      aF[rb] = *(const bf16x8*)(Ac + (wr + rb * 16 + lr) * 32 + lg * 8);
#pragma unroll
    for (int cb = 0; cb < 4; ++cb)
      bF[cb] = *(const bf16x8*)(Bc + (wc + cb * 16 + lr) * 32 + lg * 8);
#pragma unroll
    for (int rb = 0; rb < 4; ++rb)
#pragma unroll
      for (int cb = 0; cb < 4; ++cb)
        acc[rb][cb] = mfma_bf16(aF[rb], bF[cb], acc[rb][cb]);
  };

  for (int s2 = 0; s2 < 16; ++s2) {
    step(2 * s2,     As0, Bs0, As1, Bs1);
    step(2 * s2 + 1, As1, Bs1, As0, Bs0);
  }

#pragma unroll
  for (int rb = 0; rb < 4; ++rb)
#pragma unroll
    for (int cb = 0; cb < 4; ++cb)
#pragma unroll
      for (int j = 0; j < 4; ++j) {
        const int row = m0 + wr + rb * 16 + lg * 4 + j;   // C/D: col=lane&15
        const int col = n0 + wc + cb * 16 + lr;
        C[(size_t)row * ldC + col] = f2bf(acc[rb][cb][j]);
      }
}

// ---------------- fused masked attention, S^T orientation, bitmask ----------------
// (R9/R10's attention, correctness-proven.) mfma(K,Q): lane holds S[k][q]. Mask
// from the 16.8 MB packed bitmask (L2/L3-resident): one ull per (q-row, 64k-tile);
// 2 ping-ponged u64x2 pairs per qb, loaded 2 tiles ahead. 128 B/block/tile
// replaces the 32 KB strided int32 stream. K/V via global_load_lds, pre-swizzled
// source, double-buffered; raw s_barrier + vmcnt(0) at tile top.
__global__ __launch_bounds__(256) void attn_kernel(
    const unsigned short* __restrict__ Qb,
    const unsigned short* __restrict__ Kb,     // [Ms][Ee]
    const unsigned short* __restrict__ Vtb,    // [Ee][Ms]  (pre-transposed)
    const ull* __restrict__ P64,               // flat bitmask [65536 rows][32 words]
    unsigned short* __restrict__ Ob)
{
  __shared__ unsigned short Kl0[64 * 64], Kl1[64 * 64];
  __shared__ unsigned short Vl0[64 * 64], Vl1[64 * 64];
  __shared__ unsigned short Pw[4 * 32 * 72];   // per-wave P [32 q][144 B rows]

  const int tid = threadIdx.x;
  const int lane = tid & 63, w = tid >> 6;
  const int lr = lane & 15, lg = lane >> 4;

  // XCD-locality decode
  const int lid = blockIdx.x;
  const int xcd = lid & 7, slot = lid >> 3;
  const int g = xcd + 8 * (slot >> 4);           // nh group 0..31
  const int n = g >> 4, h = g & 15;
  const int q0 = (slot & 15) * 128;

  // Q fragments: wave w owns q rows [q0+32w, q0+32w+32)
  bf16x8 aQ[2][2];
#pragma unroll
  for (int qb = 0; qb < 2; ++qb) {
    const unsigned short* qp =
        Qb + ((size_t)(n * Ss + q0 + w * 32 + qb * 16 + lr)) * Ee + h * 64 + lg * 8;
    aQ[qb][0] = *(const bf16x8*)(qp);
    aQ[qb][1] = *(const bf16x8*)(qp + 32);
  }

  // staging geometry (16B chunk sig of the 8KB [64][64] tile, source pre-swizzled)
  const int sig0 = (w * 2) * 64 + lane;
  const int row0 = sig0 >> 3;
  const int c0 = (sig0 & 7) ^ (row0 & 7);
  const int row1 = row0 + 8;
  const int c1 = (sig0 & 7) ^ (row1 & 7);
  const int ldsb0 = (w * 2 + 0) * 1024;
  const int ldsb1 = (w * 2 + 1) * 1024;

  const unsigned short* kp0 = Kb + ((size_t)(n * Ss + row0) * Ee + h * 64 + c0 * 8);
  const unsigned short* kp1 = Kb + ((size_t)(n * Ss + row1) * Ee + h * 64 + c1 * 8);
  const unsigned short* vp0 = Vtb + ((size_t)(h * 64 + row0) * Ms + n * Ss + c0 * 8);
  const unsigned short* vp1 = Vtb + ((size_t)(h * 64 + row1) * Ms + n * Ss + c1 * 8);

  // bitmask row bases (ull*): one word per (row, 64k-tile)
  const ull* bmr0 = P64 + ((size_t)(n * Hh + h) * Ss + q0 + w * 32 + lr) * 32;
  const ull* bmr1 = bmr0 + 16 * 32;

  // precomputed swizzled DS byte offsets (per-thread constants)
  int koff[4][2];
#pragma unroll
  for (int cb = 0; cb < 4; ++cb) {
    const int row = cb * 16 + lr;
    koff[cb][0] = row * 128 + ((lg ^ (row & 7)) * 16);
    koff[cb][1] = row * 128 + (((4 + lg) ^ (row & 7)) * 16);
  }
  char* const PwW = (char*)Pw + w * (32 * 144);
  int pwo[2], pro[2];
#pragma unroll
  for (int qb = 0; qb < 2; ++qb) {
    pwo[qb] = (qb * 16 + lr) * 144 + lg * 8;
    pro[qb] = (qb * 16 + lr) * 144 + lg * 16;
  }

  const f32x4 zero = {0.f, 0.f, 0.f, 0.f};
  f32x4 oacc[2][4];
#pragma unroll
  for (int qb = 0; qb < 2; ++qb)
#pragma unroll
    for (int db = 0; db < 4; ++db) oacc[qb][db] = zero;
  float rs[2] = {0.f, 0.f};

  // ---- prologue: stage t0 -> buf0; bitmask pairs for tiles {0,1} and {2,3} ----
  async16(kp0, (char*)Kl0 + ldsb0);
  async16(kp1, (char*)Kl0 + ldsb1);
  async16(vp0, (char*)Vl0 + ldsb0);
  async16(vp1, (char*)Vl0 + ldsb1);
  kp0 += (size_t)64 * Ee; kp1 += (size_t)64 * Ee; vp0 += 64; vp1 += 64;

  u64x2 bmA[2], bmB[2];
  bmA[0] = *(const u64x2*)(bmr0);      bmA[1] = *(const u64x2*)(bmr1);
  bmB[0] = *(const u64x2*)(bmr0 + 2);  bmB[1] = *(const u64x2*)(bmr1 + 2);

  // tile worker: BM[qb][tp] is this tile's mask word; BMN: pair to refill (2 ahead)
  auto tile = [&](const unsigned short* KC, const unsigned short* VC,
                  unsigned short* KN, unsigned short* VN,
                  const u64x2* BM, int tp, u64x2* BMN, int tn, bool do_stage) {
    asm volatile("s_waitcnt vmcnt(0)" ::: "memory");
    __builtin_amdgcn_s_barrier();

    if (do_stage) {
      async16(kp0, (char*)KN + ldsb0);
      async16(kp1, (char*)KN + ldsb1);
      async16(vp0, (char*)VN + ldsb0);
      async16(vp1, (char*)VN + ldsb1);
      kp0 += (size_t)64 * Ee; kp1 += (size_t)64 * Ee; vp0 += 64; vp1 += 64;
    }
    if (BMN) {                          // refill dead pair with tiles {tn, tn+1}
      BMN[0] = *(const u64x2*)(bmr0 + tn);
      BMN[1] = *(const u64x2*)(bmr1 + tn);
    }

    // S^T = K Q^T per 16-k block; bit-gated exp; cvt_pk pack; ds_write_b64
#pragma unroll
    for (int cb = 0; cb < 4; ++cb) {
      const bf16x8 kF0 = *(const bf16x8*)((const char*)KC + koff[cb][0]);
      const bf16x8 kF1 = *(const bf16x8*)((const char*)KC + koff[cb][1]);
#pragma unroll
      for (int qb = 0; qb < 2; ++qb) {
        f32x4 a = mfma_bf16(kF0, aQ[qb][0], zero);
        a = mfma_bf16(kF1, aQ[qb][1], a);
        const unsigned nib =
            (unsigned)(BM[qb][tp] >> (cb * 16 + lg * 4)) & 0xFu;
        float p[4];
#pragma unroll
        for (int j = 0; j < 4; ++j)
          p[j] = (nib & (1u << j)) ? __expf(a[j] * SCALE) : 0.f;
        rs[qb] += (p[0] + p[1]) + (p[2] + p[3]);
        u32x2 pd = { cvt_pk_bf16(p[0], p[1]), cvt_pk_bf16(p[2], p[3]) };
        *(u32x2*)(PwW + pwo[qb] + cb * 32) = pd;
      }
    }

    // O += P V  (Pw rows wave-private; compiler orders the LDS RAW via lgkmcnt)
    bf16x8 aP[2][2];
#pragma unroll
    for (int qb = 0; qb < 2; ++qb) {
      aP[qb][0] = *(const bf16x8*)(PwW + pro[qb]);
      aP[qb][1] = *(const bf16x8*)(PwW + pro[qb] + 64);
    }
#pragma unroll
    for (int db = 0; db < 4; ++db) {
#pragma unroll
      for (int kc = 0; kc < 2; ++kc) {
        const bf16x8 bV = *(const bf16x8*)((const char*)VC + koff[db][kc]);
#pragma unroll
        for (int qb = 0; qb < 2; ++qb)
          oacc[qb][db] = mfma_bf16(aP[qb][kc], bV, oacc[qb][db]);
      }
    }
  };

  // period-4 schedule: bmA covers tiles {4k,4k+1}, bmB {4k+2,4k+3}.
  for (int t4 = 0; t4 < 8; ++t4) {
    const int t = t4 * 4;
    tile(Kl0, Vl0, Kl1, Vl1, bmA, 0, bmB, t + 2, true);             // t
    tile(Kl1, Vl1, Kl0, Vl0, bmA, 1, nullptr, 0, true);             // t+1
    tile(Kl0, Vl0, Kl1, Vl1, bmB, 0,
         (t4 != 7) ? bmA : nullptr, t + 4, true);                   // t+2
    tile(Kl1, Vl1, Kl0, Vl0, bmB, 1, nullptr, 0, t4 != 7);          // t+3
  }

  // rowsum: reduce across the 4 lg groups (q = qb*16+lr), then fetch per-output-q
  float inv[2][4];
#pragma unroll
  for (int qb = 0; qb < 2; ++qb) {
    float r = rs[qb];
    r += __shfl_xor(r, 16, 64);
    r += __shfl_xor(r, 32, 64);
#pragma unroll
    for (int j = 0; j < 4; ++j)
      inv[qb][j] = 1.0f / __shfl(r, lg * 4 + j, 64);
  }
#pragma unroll
  for (int qb = 0; qb < 2; ++qb)
#pragma unroll
    for (int db = 0; db < 4; ++db)
#pragma unroll
      for (int j = 0; j < 4; ++j) {
        const int qr = q0 + w * 32 + qb * 16 + lg * 4 + j;
        Ob[((size_t)(n * Ss + qr)) * Ee + h * 64 + db * 16 + lr] =
            f2bf(oacc[qb][db][j] * inv[qb][j]);
      }
}

// ---------------- output projection + bias -> fp32 --------------------------------
__global__ __launch_bounds__(256) void out_proj(
    const unsigned short* __restrict__ A,      // attn out [Ms][Ee] bf16
    const unsigned short* __restrict__ B,      // Wo [Ee][Ee] bf16
    float* __restrict__ Cf, const float* __restrict__ bias)
{
  __shared__ unsigned short As[128 * 32];
  __shared__ unsigned short Bs[128 * 32];
  constexpr int K = 1024;
  const int tid = threadIdx.x;
  const int lane = tid & 63, w = tid >> 6;
  const int lr = lane & 15, lg = lane >> 4;
  const int m0 = blockIdx.y * 128, n0 = blockIdx.x * 128;
  const int wr = (w >> 1) * 64, wc = (w & 1) * 64;

  const f32x4 zero = {0.f, 0.f, 0.f, 0.f};
  f32x4 acc[4][4];
  for (int a = 0; a < 4; ++a)
    for (int b = 0; b < 4; ++b) acc[a][b] = zero;

  for (int k0 = 0; k0 < K; k0 += 32) {
#pragma unroll
    for (int ii = 0; ii < 2; ++ii) {
      const int i = 2 * w + ii;
      const int boff = i * 1024 + lane * 16;
      const int row = boff >> 6;
      const int colb = boff & 63;
      const char* ga = (const char*)A + ((size_t)(m0 + row) * K + k0) * 2 + colb;
      const char* gb = (const char*)B + ((size_t)(n0 + row) * K + k0) * 2 + colb;
      async16(ga, (char*)As + i * 1024);
      async16(gb, (char*)Bs + i * 1024);
    }
    __syncthreads();

    bf16x8 aF[4], bF[4];
#pragma unroll
    for (int rb = 0; rb < 4; ++rb)
      aF[rb] = *(const bf16x8*)(As + (wr + rb * 16 + lr) * 32 + lg * 8);
#pragma unroll
    for (int cb = 0; cb < 4; ++cb)
      bF[cb] = *(const bf16x8*)(Bs + (wc + cb * 16 + lr) * 32 + lg * 8);
#pragma unroll
    for (int rb = 0; rb < 4; ++rb)
#pragma unroll
      for (int cb = 0; cb < 4; ++cb)
        acc[rb][cb] = mfma_bf16(aF[rb], bF[cb], acc[rb][cb]);
    __syncthreads();
  }

#pragma unroll
  for (int rb = 0; rb < 4; ++rb)
#pragma unroll
    for (int cb = 0; cb < 4; ++cb)
#pragma unroll
      for (int j = 0; j < 4; ++j) {
        const int row = m0 + wr + rb * 16 + lg * 4 + j;
        const int col = n0 + wc + cb * 16 + lr;
        Cf[(size_t)row * Ee + col] = acc[rb][cb][j] + bias[col];
      }
}

// -----------------------------------------------------------------------------------
extern "C" void kernel_launch(void* const* d_in, const int* in_sizes, int n_in,
                              void* d_out, int out_size, void* d_ws, size_t ws_size,
                              hipStream_t stream) {
  const float* qin = (const float*)d_in[0];
  const float* kin = (const float*)d_in[1];
  const float* vin = (const float*)d_in[2];
  const int*   msk = (const int*)d_in[3];
  const float* Wq  = (const float*)d_in[4];
  const float* Wk  = (const float*)d_in[5];
  const float* Wv  = (const float*)d_in[6];
  const float* Wo  = (const float*)d_in[7];
  const float* bo  = (const float*)d_in[8];
  unsigned short* ws = (unsigned short*)d_ws;
  ull* P64 = (ull*)(ws + OFF_PACK);

  // 1) convert inputs + weights to bf16
  cvt_batch<<<dim3((unsigned)(SZ_X / 4 / 256), 1, 3), 256, 0, stream>>>(
      qin, kin, vin, nullptr, ws + OFF_XQ, SZ_X, (int)(SZ_X / 4));
  cvt_batch<<<dim3((unsigned)(EEc / 4 / 256), 1, 4), 256, 0, stream>>>(
      Wq, Wk, Wv, Wo, ws + OFF_W, EEc, (int)(EEc / 4));

  // 2) QKV projections with embedded, 1-deep-pipelined mask pack
  qkv_pack<<<dim3(768), 256, 0, stream>>>(
      ws + OFF_XQ, ws + OFF_W, ws + OFF_QB, ws + OFF_VB, msk, P64);

  // 3) masked attention (1D grid 512, XCD-swizzled, bitmask-fed)
  attn_kernel<<<dim3(512), 256, 0, stream>>>(
      ws + OFF_QB, ws + OFF_KB, ws + OFF_VB, P64, ws + OFF_ATTN);

  // 4) output projection + bias -> fp32 d_out
  out_proj<<<dim3(8, 32), 256, 0, stream>>>(
      ws + OFF_ATTN, ws + OFF_W + 3 * EEc, (float*)d_out, bo);
}

// Round 12
// 228.619 us; speedup vs baseline: 1.1083x; 1.1083x over previous
//
#include <hip/hip_runtime.h>
#include <hip/hip_bf16.h>

#define DEVI __device__ __forceinline__

typedef __bf16 bf16x8 __attribute__((ext_vector_type(8)));
typedef float f32x4 __attribute__((ext_vector_type(4)));
typedef unsigned short u16x4 __attribute__((ext_vector_type(4)));
typedef unsigned int u32x2 __attribute__((ext_vector_type(2)));
typedef unsigned long long ull;
typedef int i32x4 __attribute__((ext_vector_type(4)));

constexpr int Nn = 2, Ss = 2048, Ee = 1024, Hh = 16;
constexpr int Ms = Nn * Ss;                       // 4096 rows
constexpr float SCALE = 0.022097086912079608f;    // 1/sqrt(2048) -- key-length scaling!

// workspace layout (bf16 elements)
constexpr size_t SZ_X   = (size_t)Ms * Ee;        // 4,194,304
constexpr size_t EEc    = (size_t)Ee * Ee;
constexpr size_t OFF_QB = 0;                      // Q projected [Ms][Ee]
constexpr size_t OFF_KB = SZ_X;                   // K projected [Ms][Ee]
constexpr size_t OFF_VB = 2 * SZ_X;               // V projected TRANSPOSED [Ee][Ms]
constexpr size_t OFF_XQ = 3 * SZ_X;               // bf16 inputs (3)
constexpr size_t OFF_W  = 6 * SZ_X;               // 4 weights, each Ee*Ee
constexpr size_t OFF_ATTN = OFF_XQ;               // attention out aliases XQ (dead by then)

DEVI unsigned short f2bf(float f) {               // RNE f32->bf16 (no NaN in this data)
  unsigned int u = __builtin_bit_cast(unsigned int, f);
  u += 0x7fffu + ((u >> 16) & 1u);
  return (unsigned short)(u >> 16);
}

DEVI void async16(const void* g, void* l) {
  __builtin_amdgcn_global_load_lds(
      (const __attribute__((address_space(1))) void*)g,
      (__attribute__((address_space(3))) void*)l, 16, 0, 0);
}

DEVI f32x4 mfma_bf16(bf16x8 a, bf16x8 b, f32x4 c) {
  return __builtin_amdgcn_mfma_f32_16x16x32_bf16(a, b, c, 0, 0, 0);
}

DEVI unsigned cvt_pk_bf16(float lo, float hi) {   // v_cvt_pk_bf16_f32: [hi|lo]
  unsigned r;
  asm("v_cvt_pk_bf16_f32 %0, %1, %2" : "=v"(r) : "v"(lo), "v"(hi));
  return r;
}

// ---------------- fp32 -> bf16 convert, z-batched over up to 4 sources -------------
__global__ __launch_bounds__(256) void cvt_batch(
    const float* __restrict__ s0, const float* __restrict__ s1,
    const float* __restrict__ s2, const float* __restrict__ s3,
    unsigned short* __restrict__ dbase, size_t dstride, int n4)
{
  const float* s = (blockIdx.z == 0) ? s0 : (blockIdx.z == 1) ? s1
                 : (blockIdx.z == 2) ? s2 : s3;
  unsigned short* d = dbase + (size_t)blockIdx.z * dstride;
  const int i = blockIdx.x * 256 + threadIdx.x;
  if (i >= n4) return;
  const float4 v = reinterpret_cast<const float4*>(s)[i];
  u16x4 o = { f2bf(v.x), f2bf(v.y), f2bf(v.z), f2bf(v.w) };
  reinterpret_cast<u16x4*>(d)[i] = o;
}

// ---------------- 128x128 bf16 GEMM, C = A @ B^T  (A:[M,K=1024], B:[N,K=1024]) -----
template <bool WRITE_F32>
__global__ __launch_bounds__(256) void gemm_bt(
    const unsigned short* __restrict__ Abase,
    const unsigned short* __restrict__ Bbase,
    unsigned short* __restrict__ Cbase,
    float* __restrict__ Cf,
    const float* __restrict__ bias,
    size_t strideA, size_t strideB, size_t strideC, int ldC)
{
  constexpr int K = 1024;
  __shared__ unsigned short As[128 * 32];
  __shared__ unsigned short Bs[128 * 32];

  const int z = blockIdx.z;
  const unsigned short* A = Abase + (size_t)z * strideA;
  const unsigned short* B = Bbase + (size_t)z * strideB;

  const int tid = threadIdx.x;
  const int lane = tid & 63, w = tid >> 6;
  const int lr = lane & 15, lg = lane >> 4;
  const int m0 = blockIdx.y * 128, n0 = blockIdx.x * 128;
  const int wr = (w >> 1) * 64, wc = (w & 1) * 64;

  const f32x4 zero = {0.f, 0.f, 0.f, 0.f};
  f32x4 acc[4][4];
  for (int a = 0; a < 4; ++a)
    for (int b = 0; b < 4; ++b) acc[a][b] = zero;

  for (int k0 = 0; k0 < K; k0 += 32) {
#pragma unroll
    for (int ii = 0; ii < 2; ++ii) {
      const int i = 2 * w + ii;
      const int boff = i * 1024 + lane * 16;
      const int row = boff >> 6;
      const int colb = boff & 63;
      const char* ga = (const char*)A + ((size_t)(m0 + row) * K + k0) * 2 + colb;
      const char* gb = (const char*)B + ((size_t)(n0 + row) * K + k0) * 2 + colb;
      async16(ga, (char*)As + i * 1024);
      async16(gb, (char*)Bs + i * 1024);
    }
    __syncthreads();

    bf16x8 aF[4], bF[4];
#pragma unroll
    for (int rb = 0; rb < 4; ++rb)
      aF[rb] = *(const bf16x8*)(As + (wr + rb * 16 + lr) * 32 + lg * 8);
#pragma unroll
    for (int cb = 0; cb < 4; ++cb)
      bF[cb] = *(const bf16x8*)(Bs + (wc + cb * 16 + lr) * 32 + lg * 8);
#pragma unroll
    for (int rb = 0; rb < 4; ++rb)
#pragma unroll
      for (int cb = 0; cb < 4; ++cb)
        acc[rb][cb] = mfma_bf16(aF[rb], bF[cb], acc[rb][cb]);
    __syncthreads();
  }

#pragma unroll
  for (int rb = 0; rb < 4; ++rb) {
#pragma unroll
    for (int cb = 0; cb < 4; ++cb) {
#pragma unroll
      for (int j = 0; j < 4; ++j) {
        const int row = m0 + wr + rb * 16 + lg * 4 + j;
        const int col = n0 + wc + cb * 16 + lr;
        const float v = acc[rb][cb][j];
        if constexpr (WRITE_F32) {
          Cf[(size_t)row * ldC + col] = v + bias[col];
        } else {
          unsigned short* C = Cbase + (size_t)z * strideC;
          C[(size_t)row * ldC + col] = f2bf(v);
        }
      }
    }
  }
}

// ---------------- fused masked attention, S^T orientation ---------------------------
// NEW mask path (the one change vs the 243-us R8 baseline): per tile each wave
// issues 8 NT dwordx4 loads with lanes 16g..16g+15 covering ONE ROW's contiguous
// 256 B (4 rows/instr) -- the 256B-granule pattern that measures 6.3 TB/s, vs the
// old 64B-granule tile-order reads stuck at 4.2 TB/s. The bits land in the wrong
// lanes for S^T gating, so redistribute in-wave: 4 ballots/instr + per-lane nibble
// assembly + ds_write_b8 into a wave-private LDS nibble table Mb[w][q][m];
// consumers read their byte back. 1-tile-ahead pipeline, raw s_barrier + vmcnt(0).
__global__ __launch_bounds__(256) void attn_kernel(
    const unsigned short* __restrict__ Qb,
    const unsigned short* __restrict__ Kb,     // [Ms][Ee]
    const unsigned short* __restrict__ Vtb,    // [Ee][Ms]  (pre-transposed)
    const int* __restrict__ mask,
    unsigned short* __restrict__ Ob)
{
  __shared__ unsigned short Kl0[64 * 64], Kl1[64 * 64];
  __shared__ unsigned short Vl0[64 * 64], Vl1[64 * 64];
  __shared__ unsigned short Pw[4 * 32 * 72];     // per-wave P [32 q][144 B rows]
  __shared__ unsigned char Mb[4][32][16];        // per-wave mask nibbles [q][m]

  const int tid = threadIdx.x;
  const int lane = tid & 63, w = tid >> 6;
  const int lr = lane & 15, lg = lane >> 4;

  // XCD-locality decode
  const int lid = blockIdx.x;
  const int xcd = lid & 7, slot = lid >> 3;
  const int g = xcd + 8 * (slot >> 4);           // nh group 0..31
  const int n = g >> 4, h = g & 15;
  const int q0 = (slot & 15) * 128;

  // Q fragments: wave w owns q rows [q0+32w, q0+32w+32)
  bf16x8 aQ[2][2];
#pragma unroll
  for (int qb = 0; qb < 2; ++qb) {
    const unsigned short* qp =
        Qb + ((size_t)(n * Ss + q0 + w * 32 + qb * 16 + lr)) * Ee + h * 64 + lg * 8;
    aQ[qb][0] = *(const bf16x8*)(qp);
    aQ[qb][1] = *(const bf16x8*)(qp + 32);
  }

  // K/V staging geometry (16B chunk sig of the 8KB [64][64] tile, source pre-swizzled)
  const int sig0 = (w * 2) * 64 + lane;
  const int row0 = sig0 >> 3;
  const int c0 = (sig0 & 7) ^ (row0 & 7);
  const int row1 = row0 + 8;
  const int c1 = (sig0 & 7) ^ (row1 & 7);
  const int ldsb0 = (w * 2 + 0) * 1024;
  const int ldsb1 = (w * 2 + 1) * 1024;

  const unsigned short* kp0 = Kb + ((size_t)(n * Ss + row0) * Ee + h * 64 + c0 * 8);
  const unsigned short* kp1 = Kb + ((size_t)(n * Ss + row1) * Ee + h * 64 + c1 * 8);
  const unsigned short* vp0 = Vtb + ((size_t)(h * 64 + row0) * Ms + n * Ss + c0 * 8);
  const unsigned short* vp1 = Vtb + ((size_t)(h * 64 + row1) * Ms + n * Ss + c1 * 8);

  // mask base: instr i covers rows 4i+mlg (mlg=lane>>4), cols mlr*4.. (mlr=lane&15)
  const int* mpw = mask + ((size_t)(n * Hh + h) * Ss + (q0 + w * 32 + lg)) * Ss
                        + lr * 4;

  // precomputed swizzled DS byte offsets (per-thread constants)
  int koff[4][2];
#pragma unroll
  for (int cb = 0; cb < 4; ++cb) {
    const int row = cb * 16 + lr;
    koff[cb][0] = row * 128 + ((lg ^ (row & 7)) * 16);
    koff[cb][1] = row * 128 + (((4 + lg) ^ (row & 7)) * 16);
  }
  char* const PwW = (char*)Pw + w * (32 * 144);
  int pwo[2], pro[2];
#pragma unroll
  for (int qb = 0; qb < 2; ++qb) {
    pwo[qb] = (qb * 16 + lr) * 144 + lg * 8;
    pro[qb] = (qb * 16 + lr) * 144 + lg * 16;
  }

  const f32x4 zero = {0.f, 0.f, 0.f, 0.f};
  f32x4 oacc[2][4];
#pragma unroll
  for (int qb = 0; qb < 2; ++qb)
#pragma unroll
    for (int db = 0; db < 4; ++db) oacc[qb][db] = zero;
  float rs[2] = {0.f, 0.f};

  i32x4 pm[8];                                   // mask tile in row-contig order
  auto mload = [&]() {                           // load tile at mpw (8 x 256B-granule)
#pragma unroll
    for (int i = 0; i < 8; ++i)
      pm[i] = __builtin_nontemporal_load((const i32x4*)(mpw + (size_t)(4 * i) * Ss));
    mpw += 64;
  };

  // ---- prologue: stage t0 -> buf0; mask t0 -> pm ----
  async16(kp0, (char*)Kl0 + ldsb0);
  async16(kp1, (char*)Kl0 + ldsb1);
  async16(vp0, (char*)Vl0 + ldsb0);
  async16(vp1, (char*)Vl0 + ldsb1);
  kp0 += (size_t)64 * Ee; kp1 += (size_t)64 * Ee; vp0 += 64; vp1 += 64;
  mload();

  auto tile = [&](const unsigned short* KC, const unsigned short* VC,
                  unsigned short* KN, unsigned short* VN, bool pf) {
    // stage(t) + mask(t) issued a full iteration ago -> landed; sync waves
    asm volatile("s_waitcnt vmcnt(0)" ::: "memory");
    __builtin_amdgcn_s_barrier();

    if (pf) {
      async16(kp0, (char*)KN + ldsb0);
      async16(kp1, (char*)KN + ldsb1);
      async16(vp0, (char*)VN + ldsb0);
      async16(vp1, (char*)VN + ldsb1);
      kp0 += (size_t)64 * Ee; kp1 += (size_t)64 * Ee; vp0 += 64; vp1 += 64;
    }

    // redistribute mask(t): ballots -> per-lane nibble -> wave-private LDS table
#pragma unroll
    for (int i = 0; i < 8; ++i) {
      const ull b0 = __ballot(pm[i][0] != 0);
      const ull b1 = __ballot(pm[i][1] != 0);
      const ull b2 = __ballot(pm[i][2] != 0);
      const ull b3 = __ballot(pm[i][3] != 0);
      const unsigned nib = (unsigned)((b0 >> lane) & 1)
                         | ((unsigned)((b1 >> lane) & 1) << 1)
                         | ((unsigned)((b2 >> lane) & 1) << 2)
                         | ((unsigned)((b3 >> lane) & 1) << 3);
      Mb[w][4 * i + lg][lr] = (unsigned char)nib;   // row 4i+lg, m = lr
    }
    if (pf) mload();                               // refill pm with mask(t+1)

    // S^T = K Q^T per 16-k block; nibble-gated exp; cvt_pk pack; ds_write_b64
#pragma unroll
    for (int cb = 0; cb < 4; ++cb) {
      const bf16x8 kF0 = *(const bf16x8*)((const char*)KC + koff[cb][0]);
      const bf16x8 kF1 = *(const bf16x8*)((const char*)KC + koff[cb][1]);
#pragma unroll
      for (int qb = 0; qb < 2; ++qb) {
        f32x4 a = mfma_bf16(kF0, aQ[qb][0], zero);
        a = mfma_bf16(kF1, aQ[qb][1], a);
        const unsigned nib = Mb[w][qb * 16 + lr][cb * 4 + lg];  // q row, m=cb*4+lg
        float p[4];
#pragma unroll
        for (int j = 0; j < 4; ++j)
          p[j] = ((nib >> j) & 1) ? __expf(a[j] * SCALE) : 0.f;
        rs[qb] += (p[0] + p[1]) + (p[2] + p[3]);
        u32x2 pd = { cvt_pk_bf16(p[0], p[1]), cvt_pk_bf16(p[2], p[3]) };
        *(u32x2*)(PwW + pwo[qb] + cb * 32) = pd;
      }
    }

    // O += P V  (Pw rows wave-private; compiler orders the LDS RAW via lgkmcnt)
    bf16x8 aP[2][2];
#pragma unroll
    for (int qb = 0; qb < 2; ++qb) {
      aP[qb][0] = *(const bf16x8*)(PwW + pro[qb]);
      aP[qb][1] = *(const bf16x8*)(PwW + pro[qb] + 64);
    }
#pragma unroll
    for (int db = 0; db < 4; ++db) {
#pragma unroll
      for (int kc = 0; kc < 2; ++kc) {
        const bf16x8 bV = *(const bf16x8*)((const char*)VC + koff[db][kc]);
#pragma unroll
        for (int qb = 0; qb < 2; ++qb)
          oacc[qb][db] = mfma_bf16(aP[qb][kc], bV, oacc[qb][db]);
      }
    }
  };

  for (int kt2 = 0; kt2 < 16; ++kt2) {
    tile(Kl0, Vl0, Kl1, Vl1, true);
    tile(Kl1, Vl1, Kl0, Vl0, kt2 != 15);
  }

  // rowsum: reduce across the 4 lg groups (q = qb*16+lr), then fetch per-output-q
  float inv[2][4];
#pragma unroll
  for (int qb = 0; qb < 2; ++qb) {
    float r = rs[qb];
    r += __shfl_xor(r, 16, 64);
    r += __shfl_xor(r, 32, 64);
#pragma unroll
    for (int j = 0; j < 4; ++j)
      inv[qb][j] = 1.0f / __shfl(r, lg * 4 + j, 64);
  }
#pragma unroll
  for (int qb = 0; qb < 2; ++qb)
#pragma unroll
    for (int db = 0; db < 4; ++db)
#pragma unroll
      for (int j = 0; j < 4; ++j) {
        const int qr = q0 + w * 32 + qb * 16 + lg * 4 + j;
        Ob[((size_t)(n * Ss + qr)) * Ee + h * 64 + db * 16 + lr] =
            f2bf(oacc[qb][db][j] * inv[qb][j]);
      }
}

// -----------------------------------------------------------------------------------
extern "C" void kernel_launch(void* const* d_in, const int* in_sizes, int n_in,
                              void* d_out, int out_size, void* d_ws, size_t ws_size,
                              hipStream_t stream) {
  const float* qin = (const float*)d_in[0];
  const float* kin = (const float*)d_in[1];
  const float* vin = (const float*)d_in[2];
  const int*   msk = (const int*)d_in[3];
  const float* Wq  = (const float*)d_in[4];
  const float* Wk  = (const float*)d_in[5];
  const float* Wv  = (const float*)d_in[6];
  const float* Wo  = (const float*)d_in[7];
  const float* bo  = (const float*)d_in[8];
  unsigned short* ws = (unsigned short*)d_ws;

  // 1) convert inputs + weights to bf16
  cvt_batch<<<dim3((unsigned)(SZ_X / 4 / 256), 1, 3), 256, 0, stream>>>(
      qin, kin, vin, nullptr, ws + OFF_XQ, SZ_X, (int)(SZ_X / 4));
  cvt_batch<<<dim3((unsigned)(EEc / 4 / 256), 1, 4), 256, 0, stream>>>(
      Wq, Wk, Wv, Wo, ws + OFF_W, EEc, (int)(EEc / 4));

  // 2a) Q/K projections (z-batched):  C[m][e] = X @ W^T
  gemm_bt<false><<<dim3(8, 32, 2), 256, 0, stream>>>(
      ws + OFF_XQ, ws + OFF_W, ws + OFF_QB, nullptr, nullptr,
      SZ_X, EEc, SZ_X, Ee);

  // 2b) V projection, TRANSPOSED output:  Vt[e][m] = Wv @ Xv^T
  gemm_bt<false><<<dim3(32, 8, 1), 256, 0, stream>>>(
      ws + OFF_W + 2 * EEc, ws + OFF_XQ + 2 * SZ_X, ws + OFF_VB, nullptr, nullptr,
      0, 0, 0, Ms);

  // 3) masked attention (1D grid 512, XCD-swizzled, 256B-granule mask stream)
  attn_kernel<<<dim3(512), 256, 0, stream>>>(
      ws + OFF_QB, ws + OFF_KB, ws + OFF_VB, msk, ws + OFF_ATTN);

  // 4) output projection + bias -> fp32 d_out
  gemm_bt<true><<<dim3(8, 32, 1), 256, 0, stream>>>(
      ws + OFF_ATTN, ws + OFF_W + 3 * EEc, nullptr,
      (float*)d_out, bo, 0, 0, 0, Ee);
}

// Round 13
// 214.908 us; speedup vs baseline: 1.1790x; 1.0638x over previous
//
#include <hip/hip_runtime.h>
#include <hip/hip_bf16.h>

#define DEVI __device__ __forceinline__

typedef __bf16 bf16x8 __attribute__((ext_vector_type(8)));
typedef float f32x4 __attribute__((ext_vector_type(4)));
typedef unsigned short u16x4 __attribute__((ext_vector_type(4)));
typedef unsigned int u32x2 __attribute__((ext_vector_type(2)));
typedef unsigned long long ull;
typedef int i32x4 __attribute__((ext_vector_type(4)));

constexpr int Nn = 2, Ss = 2048, Ee = 1024, Hh = 16;
constexpr int Ms = Nn * Ss;                       // 4096 rows
constexpr float SCALE = 0.022097086912079608f;    // 1/sqrt(2048) -- key-length scaling!

// workspace layout (bf16 elements)
constexpr size_t SZ_X   = (size_t)Ms * Ee;        // 4,194,304
constexpr size_t EEc    = (size_t)Ee * Ee;
constexpr size_t OFF_QB = 0;                      // Q projected [Ms][Ee]
constexpr size_t OFF_KB = SZ_X;                   // K projected [Ms][Ee]
constexpr size_t OFF_VB = 2 * SZ_X;               // V projected TRANSPOSED [Ee][Ms]
constexpr size_t OFF_XQ = 3 * SZ_X;               // bf16 inputs (3)
constexpr size_t OFF_W  = 6 * SZ_X;               // 4 weights, each Ee*Ee
constexpr size_t OFF_ATTN = OFF_XQ;               // attention out aliases XQ (dead by then)

DEVI unsigned short f2bf(float f) {               // RNE f32->bf16 (no NaN in this data)
  unsigned int u = __builtin_bit_cast(unsigned int, f);
  u += 0x7fffu + ((u >> 16) & 1u);
  return (unsigned short)(u >> 16);
}

DEVI void async16(const void* g, void* l) {
  __builtin_amdgcn_global_load_lds(
      (const __attribute__((address_space(1))) void*)g,
      (__attribute__((address_space(3))) void*)l, 16, 0, 0);
}

DEVI f32x4 mfma_bf16(bf16x8 a, bf16x8 b, f32x4 c) {
  return __builtin_amdgcn_mfma_f32_16x16x32_bf16(a, b, c, 0, 0, 0);
}

DEVI unsigned cvt_pk_bf16(float lo, float hi) {   // v_cvt_pk_bf16_f32: [hi|lo]
  unsigned r;
  asm("v_cvt_pk_bf16_f32 %0, %1, %2" : "=v"(r) : "v"(lo), "v"(hi));
  return r;
}

// ---------------- fp32 -> bf16 convert, all 7 tensors in one launch ----------------
__global__ __launch_bounds__(256) void cvt_all(
    const float* __restrict__ q, const float* __restrict__ k,
    const float* __restrict__ v, const float* __restrict__ wq,
    const float* __restrict__ wk, const float* __restrict__ wv,
    const float* __restrict__ wo, unsigned short* __restrict__ ws)
{
  const int z = blockIdx.z;
  const float* src;
  unsigned short* dst;
  int n4;
  if (z < 3) {
    src = (z == 0) ? q : (z == 1) ? k : v;
    dst = ws + OFF_XQ + (size_t)z * SZ_X;
    n4 = (int)(SZ_X / 4);
  } else {
    const int zz = z - 3;
    src = (zz == 0) ? wq : (zz == 1) ? wk : (zz == 2) ? wv : wo;
    dst = ws + OFF_W + (size_t)zz * EEc;
    n4 = (int)(EEc / 4);
  }
  const int i = blockIdx.x * 256 + threadIdx.x;
  if (i >= n4) return;
  const float4 vv = reinterpret_cast<const float4*>(src)[i];
  u16x4 o = { f2bf(vv.x), f2bf(vv.y), f2bf(vv.z), f2bf(vv.w) };
  reinterpret_cast<u16x4*>(dst)[i] = o;
}

// ---------------- m97 GEMM core: C[bf16] = A @ B^T, K=1024, 128x128 tile -----------
DEVI void gemm_core(const unsigned short* __restrict__ A,
                    const unsigned short* __restrict__ B,
                    unsigned short* __restrict__ C, int ldC,
                    int m0, int n0,
                    unsigned short* As, unsigned short* Bs)
{
  constexpr int K = 1024;
  const int tid = threadIdx.x;
  const int lane = tid & 63, w = tid >> 6;
  const int lr = lane & 15, lg = lane >> 4;
  const int wr = (w >> 1) * 64, wc = (w & 1) * 64;

  const f32x4 zero = {0.f, 0.f, 0.f, 0.f};
  f32x4 acc[4][4];
  for (int a = 0; a < 4; ++a)
    for (int b = 0; b < 4; ++b) acc[a][b] = zero;

  for (int k0 = 0; k0 < K; k0 += 32) {
#pragma unroll
    for (int ii = 0; ii < 2; ++ii) {
      const int i = 2 * w + ii;
      const int boff = i * 1024 + lane * 16;
      const int row = boff >> 6;
      const int colb = boff & 63;
      const char* ga = (const char*)A + ((size_t)(m0 + row) * K + k0) * 2 + colb;
      const char* gb = (const char*)B + ((size_t)(n0 + row) * K + k0) * 2 + colb;
      async16(ga, (char*)As + i * 1024);
      async16(gb, (char*)Bs + i * 1024);
    }
    __syncthreads();

    bf16x8 aF[4], bF[4];
#pragma unroll
    for (int rb = 0; rb < 4; ++rb)
      aF[rb] = *(const bf16x8*)(As + (wr + rb * 16 + lr) * 32 + lg * 8);
#pragma unroll
    for (int cb = 0; cb < 4; ++cb)
      bF[cb] = *(const bf16x8*)(Bs + (wc + cb * 16 + lr) * 32 + lg * 8);
#pragma unroll
    for (int rb = 0; rb < 4; ++rb)
#pragma unroll
      for (int cb = 0; cb < 4; ++cb)
        acc[rb][cb] = mfma_bf16(aF[rb], bF[cb], acc[rb][cb]);
    __syncthreads();
  }

#pragma unroll
  for (int rb = 0; rb < 4; ++rb)
#pragma unroll
    for (int cb = 0; cb < 4; ++cb)
#pragma unroll
      for (int j = 0; j < 4; ++j) {
        const int row = m0 + wr + rb * 16 + lg * 4 + j;   // C/D: col=lane&15
        const int col = n0 + wc + cb * 16 + lr;
        C[(size_t)row * ldC + col] = f2bf(acc[rb][cb][j]);
      }
}

// ---------------- merged QKV projections (one 768-block launch) --------------------
__global__ __launch_bounds__(256) void qkv3(
    const unsigned short* __restrict__ Xq,     // bf16 inputs base (3x)
    const unsigned short* __restrict__ W,      // bf16 weights base (4x)
    unsigned short* __restrict__ QKout,        // Q,K out (2x SZ_X)
    unsigned short* __restrict__ Vtout)        // V^T out [Ee][Ms]
{
  __shared__ unsigned short As[128 * 32];
  __shared__ unsigned short Bs[128 * 32];
  const int b = blockIdx.x;
  if (b < 512) {
    const int z = b >> 8, by = (b >> 3) & 31, bx = b & 7;
    gemm_core(Xq + (size_t)z * SZ_X, W + (size_t)z * EEc,
              QKout + (size_t)z * SZ_X, Ee, by * 128, bx * 128, As, Bs);
  } else {
    const int v = b - 512, bx = v & 31, by = v >> 5;
    gemm_core(W + 2 * EEc, Xq + 2 * SZ_X, Vtout, Ms, by * 128, bx * 128, As, Bs);
  }
}

// ---------------- fused masked attention, 256 q-rows/block -------------------------
// 512 threads = 8 waves x 32 q-rows (per-wave structure identical to the proven
// R12 kernel). Halves the K/V re-read count: each nh's K/V tiles are fetched by
// 8 blocks instead of 16 -> K/V HBM traffic ~270 -> ~135 MB (attention measured
// BW-saturated at 6.4 TB/s, so bytes are the only lever left).
// Mask path: 256B-granule NT loads (R12's win), nibble redistribution via
// wave-private LDS table. K/V via global_load_lds, pre-swizzled source, dbuf,
// raw s_barrier + vmcnt(0) at tile top (1-tile-ahead issue-to-wait).
__global__ __launch_bounds__(512) void attn_kernel(
    const unsigned short* __restrict__ Qb,
    const unsigned short* __restrict__ Kb,     // [Ms][Ee]
    const unsigned short* __restrict__ Vtb,    // [Ee][Ms]  (pre-transposed)
    const int* __restrict__ mask,
    unsigned short* __restrict__ Ob)
{
  __shared__ unsigned short Kl0[64 * 64], Kl1[64 * 64];
  __shared__ unsigned short Vl0[64 * 64], Vl1[64 * 64];
  __shared__ unsigned short Pw[8 * 32 * 72];     // per-wave P [32 q][144 B rows]
  __shared__ unsigned char Mb[8][32][16];        // per-wave mask nibbles [q][m]

  const int tid = threadIdx.x;
  const int lane = tid & 63, w = tid >> 6;       // w = 0..7
  const int lr = lane & 15, lg = lane >> 4;

  // XCD-locality decode: grid 256; xcd owns 4 nh-groups, 8 q-blocks each
  const int lid = blockIdx.x;
  const int xcd = lid & 7, slot = lid >> 3;      // slot 0..31
  const int g = xcd + 8 * (slot >> 3);           // nh group 0..31
  const int n = g >> 4, h = g & 15;
  const int q0 = (slot & 7) * 256;

  // Q fragments: wave w owns q rows [q0+32w, q0+32w+32)
  bf16x8 aQ[2][2];
#pragma unroll
  for (int qb = 0; qb < 2; ++qb) {
    const unsigned short* qp =
        Qb + ((size_t)(n * Ss + q0 + w * 32 + qb * 16 + lr)) * Ee + h * 64 + lg * 8;
    aQ[qb][0] = *(const bf16x8*)(qp);
    aQ[qb][1] = *(const bf16x8*)(qp + 32);
  }

  // K/V staging: 512 threads x 1 chunk per buffer (16B each), source pre-swizzled
  const int sig0 = w * 64 + lane;                // 0..511 chunk of 8KB tile
  const int row0 = sig0 >> 3;
  const int c0 = (sig0 & 7) ^ (row0 & 7);
  const int ldsb0 = w * 1024;                    // wave-uniform LDS byte base

  const unsigned short* kp0 = Kb + ((size_t)(n * Ss + row0) * Ee + h * 64 + c0 * 8);
  const unsigned short* vp0 = Vtb + ((size_t)(h * 64 + row0) * Ms + n * Ss + c0 * 8);

  // mask base: instr i covers rows 4i+lg, cols lr*4.. (256B-granule per row)
  const int* mpw = mask + ((size_t)(n * Hh + h) * Ss + (q0 + w * 32 + lg)) * Ss
                        + lr * 4;

  // precomputed swizzled DS byte offsets (per-thread constants)
  int koff[4][2];
#pragma unroll
  for (int cb = 0; cb < 4; ++cb) {
    const int row = cb * 16 + lr;
    koff[cb][0] = row * 128 + ((lg ^ (row & 7)) * 16);
    koff[cb][1] = row * 128 + (((4 + lg) ^ (row & 7)) * 16);
  }
  char* const PwW = (char*)Pw + w * (32 * 144);
  int pwo[2], pro[2];
#pragma unroll
  for (int qb = 0; qb < 2; ++qb) {
    pwo[qb] = (qb * 16 + lr) * 144 + lg * 8;
    pro[qb] = (qb * 16 + lr) * 144 + lg * 16;
  }

  const f32x4 zero = {0.f, 0.f, 0.f, 0.f};
  f32x4 oacc[2][4];
#pragma unroll
  for (int qb = 0; qb < 2; ++qb)
#pragma unroll
    for (int db = 0; db < 4; ++db) oacc[qb][db] = zero;
  float rs[2] = {0.f, 0.f};

  i32x4 pm[8];                                   // mask tile, row-contig 256B chunks
  auto mload = [&]() {
#pragma unroll
    for (int i = 0; i < 8; ++i)
      pm[i] = __builtin_nontemporal_load((const i32x4*)(mpw + (size_t)(4 * i) * Ss));
    mpw += 64;
  };

  // ---- prologue: stage t0 -> buf0; mask t0 -> pm ----
  async16(kp0, (char*)Kl0 + ldsb0);
  async16(vp0, (char*)Vl0 + ldsb0);
  kp0 += (size_t)64 * Ee; vp0 += 64;
  mload();

  auto tile = [&](const unsigned short* KC, const unsigned short* VC,
                  unsigned short* KN, unsigned short* VN, bool pf) {
    // stage(t) + mask(t) issued a full iteration ago -> landed; sync waves
    asm volatile("s_waitcnt vmcnt(0)" ::: "memory");
    __builtin_amdgcn_s_barrier();

    if (pf) {
      async16(kp0, (char*)KN + ldsb0);
      async16(vp0, (char*)VN + ldsb0);
      kp0 += (size_t)64 * Ee; vp0 += 64;
    }

    // redistribute mask(t): per-lane nibble pack -> wave-private LDS table
#pragma unroll
    for (int i = 0; i < 8; ++i) {
      const unsigned nib = (pm[i][0] != 0 ? 1u : 0u)
                         | (pm[i][1] != 0 ? 2u : 0u)
                         | (pm[i][2] != 0 ? 4u : 0u)
                         | (pm[i][3] != 0 ? 8u : 0u);
      Mb[w][4 * i + lg][lr] = (unsigned char)nib;   // row 4i+lg, m = lr
    }
    if (pf) mload();                               // refill pm with mask(t+1)

    // S^T = K Q^T per 16-k block; nibble-gated exp; cvt_pk pack; ds_write_b64
#pragma unroll
    for (int cb = 0; cb < 4; ++cb) {
      const bf16x8 kF0 = *(const bf16x8*)((const char*)KC + koff[cb][0]);
      const bf16x8 kF1 = *(const bf16x8*)((const char*)KC + koff[cb][1]);
#pragma unroll
      for (int qb = 0; qb < 2; ++qb) {
        f32x4 a = mfma_bf16(kF0, aQ[qb][0], zero);
        a = mfma_bf16(kF1, aQ[qb][1], a);
        const unsigned nib = Mb[w][qb * 16 + lr][cb * 4 + lg];  // q row, m=cb*4+lg
        float p[4];
#pragma unroll
        for (int j = 0; j < 4; ++j)
          p[j] = ((nib >> j) & 1) ? __expf(a[j] * SCALE) : 0.f;
        rs[qb] += (p[0] + p[1]) + (p[2] + p[3]);
        u32x2 pd = { cvt_pk_bf16(p[0], p[1]), cvt_pk_bf16(p[2], p[3]) };
        *(u32x2*)(PwW + pwo[qb] + cb * 32) = pd;
      }
    }

    // O += P V  (Pw rows wave-private; compiler orders the LDS RAW via lgkmcnt)
    bf16x8 aP[2][2];
#pragma unroll
    for (int qb = 0; qb < 2; ++qb) {
      aP[qb][0] = *(const bf16x8*)(PwW + pro[qb]);
      aP[qb][1] = *(const bf16x8*)(PwW + pro[qb] + 64);
    }
#pragma unroll
    for (int db = 0; db < 4; ++db) {
#pragma unroll
      for (int kc = 0; kc < 2; ++kc) {
        const bf16x8 bV = *(const bf16x8*)((const char*)VC + koff[db][kc]);
#pragma unroll
        for (int qb = 0; qb < 2; ++qb)
          oacc[qb][db] = mfma_bf16(aP[qb][kc], bV, oacc[qb][db]);
      }
    }
  };

  for (int kt2 = 0; kt2 < 16; ++kt2) {
    tile(Kl0, Vl0, Kl1, Vl1, true);
    tile(Kl1, Vl1, Kl0, Vl0, kt2 != 15);
  }

  // rowsum: reduce across the 4 lg groups (q = qb*16+lr), then fetch per-output-q
  float inv[2][4];
#pragma unroll
  for (int qb = 0; qb < 2; ++qb) {
    float r = rs[qb];
    r += __shfl_xor(r, 16, 64);
    r += __shfl_xor(r, 32, 64);
#pragma unroll
    for (int j = 0; j < 4; ++j)
      inv[qb][j] = 1.0f / __shfl(r, lg * 4 + j, 64);
  }
#pragma unroll
  for (int qb = 0; qb < 2; ++qb)
#pragma unroll
    for (int db = 0; db < 4; ++db)
#pragma unroll
      for (int j = 0; j < 4; ++j) {
        const int qr = q0 + w * 32 + qb * 16 + lg * 4 + j;
        Ob[((size_t)(n * Ss + qr)) * Ee + h * 64 + db * 16 + lr] =
            f2bf(oacc[qb][db][j] * inv[qb][j]);
      }
}

// ---------------- output projection + bias -> fp32 --------------------------------
__global__ __launch_bounds__(256) void out_proj(
    const unsigned short* __restrict__ A,      // attn out [Ms][Ee] bf16
    const unsigned short* __restrict__ B,      // Wo [Ee][Ee] bf16
    float* __restrict__ Cf, const float* __restrict__ bias)
{
  __shared__ unsigned short As[128 * 32];
  __shared__ unsigned short Bs[128 * 32];
  constexpr int K = 1024;
  const int tid = threadIdx.x;
  const int lane = tid & 63, w = tid >> 6;
  const int lr = lane & 15, lg = lane >> 4;
  const int m0 = blockIdx.y * 128, n0 = blockIdx.x * 128;
  const int wr = (w >> 1) * 64, wc = (w & 1) * 64;

  const f32x4 zero = {0.f, 0.f, 0.f, 0.f};
  f32x4 acc[4][4];
  for (int a = 0; a < 4; ++a)
    for (int b = 0; b < 4; ++b) acc[a][b] = zero;

  for (int k0 = 0; k0 < K; k0 += 32) {
#pragma unroll
    for (int ii = 0; ii < 2; ++ii) {
      const int i = 2 * w + ii;
      const int boff = i * 1024 + lane * 16;
      const int row = boff >> 6;
      const int colb = boff & 63;
      const char* ga = (const char*)A + ((size_t)(m0 + row) * K + k0) * 2 + colb;
      const char* gb = (const char*)B + ((size_t)(n0 + row) * K + k0) * 2 + colb;
      async16(ga, (char*)As + i * 1024);
      async16(gb, (char*)Bs + i * 1024);
    }
    __syncthreads();

    bf16x8 aF[4], bF[4];
#pragma unroll
    for (int rb = 0; rb < 4; ++rb)
      aF[rb] = *(const bf16x8*)(As + (wr + rb * 16 + lr) * 32 + lg * 8);
#pragma unroll
    for (int cb = 0; cb < 4; ++cb)
      bF[cb] = *(const bf16x8*)(Bs + (wc + cb * 16 + lr) * 32 + lg * 8);
#pragma unroll
    for (int rb = 0; rb < 4; ++rb)
#pragma unroll
      for (int cb = 0; cb < 4; ++cb)
        acc[rb][cb] = mfma_bf16(aF[rb], bF[cb], acc[rb][cb]);
    __syncthreads();
  }

#pragma unroll
  for (int rb = 0; rb < 4; ++rb)
#pragma unroll
    for (int cb = 0; cb < 4; ++cb)
#pragma unroll
      for (int j = 0; j < 4; ++j) {
        const int row = m0 + wr + rb * 16 + lg * 4 + j;
        const int col = n0 + wc + cb * 16 + lr;
        Cf[(size_t)row * Ee + col] = acc[rb][cb][j] + bias[col];
      }
}

// -----------------------------------------------------------------------------------
extern "C" void kernel_launch(void* const* d_in, const int* in_sizes, int n_in,
                              void* d_out, int out_size, void* d_ws, size_t ws_size,
                              hipStream_t stream) {
  const float* qin = (const float*)d_in[0];
  const float* kin = (const float*)d_in[1];
  const float* vin = (const float*)d_in[2];
  const int*   msk = (const int*)d_in[3];
  const float* Wq  = (const float*)d_in[4];
  const float* Wk  = (const float*)d_in[5];
  const float* Wv  = (const float*)d_in[6];
  const float* Wo  = (const float*)d_in[7];
  const float* bo  = (const float*)d_in[8];
  unsigned short* ws = (unsigned short*)d_ws;

  // 1) convert inputs + weights to bf16 (single launch, 7 z-slices)
  cvt_all<<<dim3((unsigned)(SZ_X / 4 / 256), 1, 7), 256, 0, stream>>>(
      qin, kin, vin, Wq, Wk, Wv, Wo, ws);

  // 2) Q/K projections + V^T projection (single 768-block launch)
  qkv3<<<dim3(768), 256, 0, stream>>>(
      ws + OFF_XQ, ws + OFF_W, ws + OFF_QB, ws + OFF_VB);

  // 3) masked attention (grid 256, 512 threads, 256 q-rows/block)
  attn_kernel<<<dim3(256), 512, 0, stream>>>(
      ws + OFF_QB, ws + OFF_KB, ws + OFF_VB, msk, ws + OFF_ATTN);

  // 4) output projection + bias -> fp32 d_out
  out_proj<<<dim3(8, 32), 256, 0, stream>>>(
      ws + OFF_ATTN, ws + OFF_W + 3 * EEc, (float*)d_out, bo);
}